// Round 1
// baseline (71.236 us; speedup 1.0000x reference)
//
#include <hip/hip_runtime.h>

constexpr int N_NODES   = 50000;
constexpr int N_EDGES   = 800000;
constexpr int D_FEAT    = 96;
constexpr int DIM_H     = 128;
constexpr int N_CLASSES = 10;

// ---------------------------------------------------------------------------
// k1: y[i] = x[i,:] . a1   (rank-1 first layer collapses row to scalar)
// ---------------------------------------------------------------------------
__global__ void k_node_dot(const float* __restrict__ x,
                           const float* __restrict__ a1,
                           float* __restrict__ y) {
    int i = blockIdx.x * blockDim.x + threadIdx.x;
    if (i >= N_NODES) return;
    const float4* row = reinterpret_cast<const float4*>(x + (size_t)i * D_FEAT);
    const float4* av  = reinterpret_cast<const float4*>(a1);
    float acc = 0.f;
#pragma unroll
    for (int k = 0; k < D_FEAT / 4; ++k) {
        float4 v = row[k];
        float4 a = av[k];
        acc += v.x * a.x + v.y * a.y + v.z * a.z + v.w * a.w;
    }
    y[i] = acc;
}

// ---------------------------------------------------------------------------
// k2: s[dst[e]] += y[src[e]]   (scalar segment-sum over edges)
// ---------------------------------------------------------------------------
__global__ void k_scatter(const int* __restrict__ src,
                          const int* __restrict__ dst,
                          const float* __restrict__ y,
                          float* __restrict__ s) {
    int e = blockIdx.x * blockDim.x + threadIdx.x;
    if (e >= N_EDGES) return;
    atomicAdd(&s[dst[e]], y[src[e]]);
}

// ---------------------------------------------------------------------------
// k3: P = sum max(s,0); M = sum min(s,0)
// ---------------------------------------------------------------------------
__global__ void k_reduce(const float* __restrict__ s, float* __restrict__ PM) {
    float p = 0.f, m = 0.f;
    for (int i = blockIdx.x * blockDim.x + threadIdx.x; i < N_NODES;
         i += gridDim.x * blockDim.x) {
        float v = s[i];
        p += fmaxf(v, 0.f);
        m += fminf(v, 0.f);
    }
    for (int off = 32; off > 0; off >>= 1) {
        p += __shfl_down(p, off);
        m += __shfl_down(m, off);
    }
    __shared__ float lp[4], lm[4];
    int wid = threadIdx.x >> 6, lane = threadIdx.x & 63;
    if (lane == 0) { lp[wid] = p; lm[wid] = m; }
    __syncthreads();
    if (threadIdx.x == 0) {
        float tp = 0.f, tm = 0.f;
        int nw = blockDim.x >> 6;
        for (int w = 0; w < nw; ++w) { tp += lp[w]; tm += lm[w]; }
        atomicAdd(&PM[0], tp);
        atomicAdd(&PM[1], tm);
    }
}

// ---------------------------------------------------------------------------
// k4: cp = sum_{b1>0} a2*b1 ; cn = sum_{b1<0} a2*b1 ; out = (P*cp+M*cn)*b2
// ---------------------------------------------------------------------------
__global__ void k_final(const float* __restrict__ b1,
                        const float* __restrict__ a2,
                        const float* __restrict__ b2,
                        const float* __restrict__ PM,
                        float* __restrict__ out) {
    int t = threadIdx.x;  // 128 threads == DIM_H
    float bv = b1[t];
    float prod = a2[t] * bv;
    float cp = (bv > 0.f) ? prod : 0.f;
    float cn = (bv < 0.f) ? prod : 0.f;
    for (int off = 32; off > 0; off >>= 1) {
        cp += __shfl_down(cp, off);
        cn += __shfl_down(cn, off);
    }
    __shared__ float scp[2], scn[2];
    __shared__ float tval;
    if ((t & 63) == 0) { scp[t >> 6] = cp; scn[t >> 6] = cn; }
    __syncthreads();
    if (t == 0) {
        float CP = scp[0] + scp[1];
        float CN = scn[0] + scn[1];
        tval = PM[0] * CP + PM[1] * CN;
    }
    __syncthreads();
    if (t < N_CLASSES) out[t] = tval * b2[t];
}

extern "C" void kernel_launch(void* const* d_in, const int* in_sizes, int n_in,
                              void* d_out, int out_size, void* d_ws, size_t ws_size,
                              hipStream_t stream) {
    const float* x  = (const float*)d_in[0];
    const int*   ei = (const int*)d_in[1];   // edge_index flat: [src(800000), dst(800000)]
    const float* a1 = (const float*)d_in[2];
    const float* b1 = (const float*)d_in[3];
    const float* a2 = (const float*)d_in[4];
    const float* b2 = (const float*)d_in[5];
    float* out = (float*)d_out;

    // workspace layout: y[N_NODES] | s[N_NODES] | PM[2]
    float* y  = (float*)d_ws;
    float* s  = y + N_NODES;
    float* PM = s + N_NODES;

    // zero the accumulation buffers (ws is poisoned, not re-zeroed by harness)
    hipMemsetAsync(s, 0, (N_NODES + 2) * sizeof(float), stream);

    k_node_dot<<<(N_NODES + 255) / 256, 256, 0, stream>>>(x, a1, y);
    k_scatter<<<(N_EDGES + 255) / 256, 256, 0, stream>>>(ei, ei + N_EDGES, y, s);
    k_reduce<<<196, 256, 0, stream>>>(s, PM);
    k_final<<<1, DIM_H, 0, stream>>>(b1, a2, b2, PM, out);
}

// Round 2
// 66.163 us; speedup vs baseline: 1.0767x; 1.0767x over previous
//
#include <hip/hip_runtime.h>

constexpr int N_NODES   = 50000;
constexpr int N_EDGES   = 800000;
constexpr int D_FEAT    = 96;
constexpr int DIM_H     = 128;
constexpr int N_CLASSES = 10;
constexpr int N_REP     = 8;   // one accumulator replica per XCD

// ---------------------------------------------------------------------------
// k1: y[i] = x[i,:] . a1   (rank-1 first layer collapses row to scalar)
// ---------------------------------------------------------------------------
__global__ void k_node_dot(const float* __restrict__ x,
                           const float* __restrict__ a1,
                           float* __restrict__ y) {
    int i = blockIdx.x * blockDim.x + threadIdx.x;
    if (i >= N_NODES) return;
    const float4* row = reinterpret_cast<const float4*>(x + (size_t)i * D_FEAT);
    const float4* av  = reinterpret_cast<const float4*>(a1);
    float acc = 0.f;
#pragma unroll
    for (int k = 0; k < D_FEAT / 4; ++k) {
        float4 v = row[k];
        float4 a = av[k];
        acc += v.x * a.x + v.y * a.y + v.z * a.z + v.w * a.w;
    }
    y[i] = acc;
}

// ---------------------------------------------------------------------------
// k2 (replicated): srep[xcd][dst[e]] += y[src[e]] with WORKGROUP-scope atomics.
// No sc1 -> the RMW executes in the local XCD's L2 (atomic for all blocks on
// that XCD). Each XCD owns its replica, so cross-XCD L2 non-coherence is
// irrelevant; kernel-end flush publishes the replicas to the next kernel.
// ---------------------------------------------------------------------------
__global__ void k_scatter_rep(const int* __restrict__ src,
                              const int* __restrict__ dst,
                              const float* __restrict__ y,
                              float* __restrict__ srep) {
    int xcd;
    asm volatile("s_getreg_b32 %0, hwreg(HW_REG_XCC_ID)" : "=s"(xcd));
    float* s = srep + (size_t)(xcd & (N_REP - 1)) * N_NODES;
    int e = blockIdx.x * blockDim.x + threadIdx.x;
    if (e >= N_EDGES) return;
    float v = y[src[e]];
    __hip_atomic_fetch_add(&s[dst[e]], v, __ATOMIC_RELAXED,
                           __HIP_MEMORY_SCOPE_WORKGROUP);
}

// fallback (device-scope, single array) if ws is too small for replicas
__global__ void k_scatter(const int* __restrict__ src,
                          const int* __restrict__ dst,
                          const float* __restrict__ y,
                          float* __restrict__ s) {
    int e = blockIdx.x * blockDim.x + threadIdx.x;
    if (e >= N_EDGES) return;
    atomicAdd(&s[dst[e]], y[src[e]]);
}

// ---------------------------------------------------------------------------
// k3: fold replicas, then P = sum max(s,0); M = sum min(s,0)
// ---------------------------------------------------------------------------
template <int NR>
__global__ void k_reduce(const float* __restrict__ srep, float* __restrict__ PM) {
    float p = 0.f, m = 0.f;
    for (int i = blockIdx.x * blockDim.x + threadIdx.x; i < N_NODES;
         i += gridDim.x * blockDim.x) {
        float v = 0.f;
#pragma unroll
        for (int r = 0; r < NR; ++r) v += srep[(size_t)r * N_NODES + i];
        p += fmaxf(v, 0.f);
        m += fminf(v, 0.f);
    }
    for (int off = 32; off > 0; off >>= 1) {
        p += __shfl_down(p, off);
        m += __shfl_down(m, off);
    }
    __shared__ float lp[4], lm[4];
    int wid = threadIdx.x >> 6, lane = threadIdx.x & 63;
    if (lane == 0) { lp[wid] = p; lm[wid] = m; }
    __syncthreads();
    if (threadIdx.x == 0) {
        float tp = 0.f, tm = 0.f;
        int nw = blockDim.x >> 6;
        for (int w = 0; w < nw; ++w) { tp += lp[w]; tm += lm[w]; }
        atomicAdd(&PM[0], tp);
        atomicAdd(&PM[1], tm);
    }
}

// ---------------------------------------------------------------------------
// k4: cp = sum_{b1>0} a2*b1 ; cn = sum_{b1<0} a2*b1 ; out = (P*cp+M*cn)*b2
// ---------------------------------------------------------------------------
__global__ void k_final(const float* __restrict__ b1,
                        const float* __restrict__ a2,
                        const float* __restrict__ b2,
                        const float* __restrict__ PM,
                        float* __restrict__ out) {
    int t = threadIdx.x;  // 128 threads == DIM_H
    float bv = b1[t];
    float prod = a2[t] * bv;
    float cp = (bv > 0.f) ? prod : 0.f;
    float cn = (bv < 0.f) ? prod : 0.f;
    for (int off = 32; off > 0; off >>= 1) {
        cp += __shfl_down(cp, off);
        cn += __shfl_down(cn, off);
    }
    __shared__ float scp[2], scn[2];
    __shared__ float tval;
    if ((t & 63) == 0) { scp[t >> 6] = cp; scn[t >> 6] = cn; }
    __syncthreads();
    if (t == 0) {
        float CP = scp[0] + scp[1];
        float CN = scn[0] + scn[1];
        tval = PM[0] * CP + PM[1] * CN;
    }
    __syncthreads();
    if (t < N_CLASSES) out[t] = tval * b2[t];
}

extern "C" void kernel_launch(void* const* d_in, const int* in_sizes, int n_in,
                              void* d_out, int out_size, void* d_ws, size_t ws_size,
                              hipStream_t stream) {
    const float* x  = (const float*)d_in[0];
    const int*   ei = (const int*)d_in[1];   // edge_index flat: [src(800000), dst(800000)]
    const float* a1 = (const float*)d_in[2];
    const float* b1 = (const float*)d_in[3];
    const float* a2 = (const float*)d_in[4];
    const float* b2 = (const float*)d_in[5];
    float* out = (float*)d_out;

    // ws layout: y[N_NODES] | srep[N_REP*N_NODES] | PM[2]
    float* y    = (float*)d_ws;
    float* srep = y + N_NODES;
    float* PM   = srep + (size_t)N_REP * N_NODES;

    size_t need = ((size_t)N_NODES * (N_REP + 1) + 2) * sizeof(float);
    bool replicated = ws_size >= need;

    if (replicated) {
        hipMemsetAsync(srep, 0, ((size_t)N_REP * N_NODES + 2) * sizeof(float), stream);
        k_node_dot<<<(N_NODES + 255) / 256, 256, 0, stream>>>(x, a1, y);
        k_scatter_rep<<<(N_EDGES + 255) / 256, 256, 0, stream>>>(ei, ei + N_EDGES, y, srep);
        k_reduce<N_REP><<<196, 256, 0, stream>>>(srep, PM);
        k_final<<<1, DIM_H, 0, stream>>>(b1, a2, b2, PM, out);
    } else {
        // fallback: single accumulator, device-scope atomics
        float* s  = y + N_NODES;
        float* PM2 = s + N_NODES;
        hipMemsetAsync(s, 0, (N_NODES + 2) * sizeof(float), stream);
        k_node_dot<<<(N_NODES + 255) / 256, 256, 0, stream>>>(x, a1, y);
        k_scatter<<<(N_EDGES + 255) / 256, 256, 0, stream>>>(ei, ei + N_EDGES, y, s);
        k_reduce<1><<<196, 256, 0, stream>>>(s, PM2);
        k_final<<<1, DIM_H, 0, stream>>>(b1, a2, b2, PM2, out);
    }
}

// Round 3
// 48.827 us; speedup vs baseline: 1.4589x; 1.3550x over previous
//
#include <hip/hip_runtime.h>

constexpr int N_NODES   = 50000;
constexpr int N_EDGES   = 800000;
constexpr int D_FEAT    = 96;
constexpr int DIM_H     = 128;
constexpr int N_CLASSES = 10;

constexpr int SHIFT        = 9;                      // 512 nodes per bucket
constexpr int BUCKET_NODES = 1 << SHIFT;
constexpr int NB           = (N_NODES + BUCKET_NODES - 1) >> SHIFT;  // 98
constexpr int NBLK1        = 256;                    // phase-1 blocks
constexpr int EPB          = N_EDGES / NBLK1;        // 3125 edges/block (exact)
constexpr int PREFW        = NB + 1;                 // 99

// inclusive scan within a 64-lane wave
__device__ inline int wave_iscan(int v, int lane) {
#pragma unroll
    for (int off = 1; off < 64; off <<= 1) {
        int n = __shfl_up(v, off);
        if (lane >= off) v += n;
    }
    return v;
}

// ---------------------------------------------------------------------------
// k1: y[i] = x[i,:] . a1   (rank-1 first layer collapses row to scalar)
// ---------------------------------------------------------------------------
__global__ void k_node_dot(const float* __restrict__ x,
                           const float* __restrict__ a1,
                           float* __restrict__ y) {
    int i = blockIdx.x * blockDim.x + threadIdx.x;
    if (i >= N_NODES) return;
    const float4* row = reinterpret_cast<const float4*>(x + (size_t)i * D_FEAT);
    const float4* av  = reinterpret_cast<const float4*>(a1);
    float acc = 0.f;
#pragma unroll
    for (int k = 0; k < D_FEAT / 4; ++k) {
        float4 v = row[k];
        float4 a = av[k];
        acc += v.x * a.x + v.y * a.y + v.z * a.z + v.w * a.w;
    }
    y[i] = acc;
}

// ---------------------------------------------------------------------------
// k2 (phase 1): bin edges by dst bucket into per-block regions. NO global
// atomics: per-block LDS histogram -> scan -> grouped 8B pair writes.
// pairs[blk*EPB + pos] = (f32 y[src] <<32) | dst ;  prefg[blk][b] = excl scan
// ---------------------------------------------------------------------------
__global__ __launch_bounds__(256) void k_bin(const int* __restrict__ src,
                                             const int* __restrict__ dst,
                                             const float* __restrict__ y,
                                             unsigned long long* __restrict__ pairs,
                                             int* __restrict__ prefg) {
    __shared__ int hist[NB];
    __shared__ int run[NB];
    __shared__ int excl[PREFW];
    __shared__ int wsum[4];
    const int tid  = threadIdx.x;
    const int lane = tid & 63, wid = tid >> 6;
    const int blk  = blockIdx.x;
    const int e0   = blk * EPB;

    for (int b = tid; b < NB; b += 256) hist[b] = 0;
    __syncthreads();

    // pass A: histogram of dst buckets
    for (int j = tid; j < EPB; j += 256) {
        int d = dst[e0 + j];
        atomicAdd(&hist[d >> SHIFT], 1);
    }
    __syncthreads();

    // exclusive scan over NB entries (all 4 waves run; waves with tid>=NB add 0)
    int v   = (tid < NB) ? hist[tid] : 0;
    int inc = wave_iscan(v, lane);
    if (lane == 63) wsum[wid] = inc;
    __syncthreads();
    int woff = 0;
#pragma unroll
    for (int w = 0; w < 4; ++w) if (w < wid) woff += wsum[w];
    if (tid < NB) {
        int e = inc - v + woff;
        excl[tid] = e;
        run[tid]  = e;
    }
    if (tid == 0) excl[NB] = wsum[0] + wsum[1] + wsum[2] + wsum[3];
    __syncthreads();
    if (tid < PREFW) prefg[blk * PREFW + tid] = excl[tid];

    // pass B: scatter pairs grouped by bucket within this block's region
    for (int j = tid; j < EPB; j += 256) {
        int   d = dst[e0 + j];
        int   s = src[e0 + j];
        float w = y[s];
        int   b = d >> SHIFT;
        int pos = atomicAdd(&run[b], 1);
        pairs[(size_t)blk * EPB + pos] =
            ((unsigned long long)__float_as_uint(w) << 32) | (unsigned int)d;
    }
}

// ---------------------------------------------------------------------------
// k3 (phase 2): one block per bucket. Gather this bucket's segments from all
// 256 regions (flattened via binary search for load balance), accumulate in
// LDS, then emit partial P (relu+) and M (relu-) sums. s[] never hits global.
// ---------------------------------------------------------------------------
__global__ __launch_bounds__(512) void k_accum(const unsigned long long* __restrict__ pairs,
                                               const int* __restrict__ prefg,
                                               float* __restrict__ PMpart) {
    __shared__ float acc[BUCKET_NODES];
    __shared__ int soff[NBLK1];
    __shared__ int ooff[NBLK1 + 1];
    __shared__ int wsum[8];
    __shared__ float rp[8], rm[8];
    const int b    = blockIdx.x;
    const int tid  = threadIdx.x;
    const int lane = tid & 63, wid = tid >> 6;

    for (int i = tid; i < BUCKET_NODES; i += 512) acc[i] = 0.f;

    // segment descriptors: count + start per source block
    int cnt = 0;
    if (tid < NBLK1) {
        int st = prefg[tid * PREFW + b];
        int en = prefg[tid * PREFW + b + 1];
        soff[tid] = st;
        cnt = en - st;
    }
    int inc = wave_iscan(cnt, lane);
    if (lane == 63) wsum[wid] = inc;
    __syncthreads();
    int woff = 0;
#pragma unroll
    for (int w = 0; w < 8; ++w) if (w < wid) woff += wsum[w];
    if (tid < NBLK1) ooff[tid] = inc - cnt + woff;
    if (tid == 0) {
        int t = 0;
#pragma unroll
        for (int w = 0; w < 8; ++w) t += wsum[w];
        ooff[NBLK1] = t;
    }
    __syncthreads();

    const int T = ooff[NBLK1];
    // flattened gather, 4-deep software pipeline (static indexing only)
    for (int k0 = tid; k0 < T; k0 += 512 * 4) {
        int  kk0 = k0,          kk1 = k0 + 512,  kk2 = k0 + 1024, kk3 = k0 + 1536;
        bool ok0 = kk0 < T,     ok1 = kk1 < T,   ok2 = kk2 < T,   ok3 = kk3 < T;
        unsigned long long p0 = 0, p1 = 0, p2 = 0, p3 = 0;
#define FIND_LOAD(OK, KK, P)                                                    \
        if (OK) {                                                               \
            int lo = 0, hi = NBLK1;                                             \
            while (hi - lo > 1) { int mid = (lo + hi) >> 1;                     \
                                  if (ooff[mid] <= KK) lo = mid; else hi = mid; } \
            int j = KK - ooff[lo];                                              \
            P = pairs[(size_t)lo * EPB + soff[lo] + j];                         \
        }
        FIND_LOAD(ok0, kk0, p0)
        FIND_LOAD(ok1, kk1, p1)
        FIND_LOAD(ok2, kk2, p2)
        FIND_LOAD(ok3, kk3, p3)
#undef FIND_LOAD
#define ACCUM(OK, P)                                                            \
        if (OK) {                                                               \
            int   d = (int)(P & 0xffffffffu);                                   \
            float v = __uint_as_float((unsigned int)(P >> 32));                 \
            atomicAdd(&acc[d & (BUCKET_NODES - 1)], v);                         \
        }
        ACCUM(ok0, p0)
        ACCUM(ok1, p1)
        ACCUM(ok2, p2)
        ACCUM(ok3, p3)
#undef ACCUM
    }
    __syncthreads();

    // relu-split partial sums for this bucket
    float p = 0.f, m = 0.f;
    const int gbase = b << SHIFT;
    for (int i = tid; i < BUCKET_NODES; i += 512) {
        if (gbase + i < N_NODES) {
            float vv = acc[i];
            p += fmaxf(vv, 0.f);
            m += fminf(vv, 0.f);
        }
    }
#pragma unroll
    for (int off = 32; off > 0; off >>= 1) {
        p += __shfl_down(p, off);
        m += __shfl_down(m, off);
    }
    if (lane == 0) { rp[wid] = p; rm[wid] = m; }
    __syncthreads();
    if (tid == 0) {
        float tp = 0.f, tm = 0.f;
#pragma unroll
        for (int w = 0; w < 8; ++w) { tp += rp[w]; tm += rm[w]; }
        PMpart[2 * b]     = tp;
        PMpart[2 * b + 1] = tm;
    }
}

// ---------------------------------------------------------------------------
// k4: P=sum rp, M=sum rm; cp=sum_{b1>0}a2*b1; cn=sum_{b1<0}a2*b1;
//     out = (P*cp + M*cn) * b2
// ---------------------------------------------------------------------------
__global__ void k_final(const float* __restrict__ b1,
                        const float* __restrict__ a2,
                        const float* __restrict__ b2,
                        const float* __restrict__ PMpart,
                        float* __restrict__ out) {
    int t = threadIdx.x;  // 128 threads
    float p = 0.f, m = 0.f;
    if (t < NB) { p = PMpart[2 * t]; m = PMpart[2 * t + 1]; }
    float bv   = b1[t];
    float prod = a2[t] * bv;
    float cp = (bv > 0.f) ? prod : 0.f;
    float cn = (bv < 0.f) ? prod : 0.f;
#pragma unroll
    for (int off = 32; off > 0; off >>= 1) {
        p  += __shfl_down(p, off);
        m  += __shfl_down(m, off);
        cp += __shfl_down(cp, off);
        cn += __shfl_down(cn, off);
    }
    __shared__ float sp[2], sm[2], scp[2], scn[2];
    __shared__ float tval;
    if ((t & 63) == 0) {
        int w = t >> 6;
        sp[w] = p; sm[w] = m; scp[w] = cp; scn[w] = cn;
    }
    __syncthreads();
    if (t == 0) {
        float P  = sp[0] + sp[1];
        float M  = sm[0] + sm[1];
        float CP = scp[0] + scp[1];
        float CN = scn[0] + scn[1];
        tval = P * CP + M * CN;
    }
    __syncthreads();
    if (t < N_CLASSES) out[t] = tval * b2[t];
}

// ---------------------------------------------------------------------------
// fallback path (ws too small): device-scope atomic scatter (round-1 kernel)
// ---------------------------------------------------------------------------
__global__ void k_scatter(const int* __restrict__ src,
                          const int* __restrict__ dst,
                          const float* __restrict__ y,
                          float* __restrict__ s) {
    int e = blockIdx.x * blockDim.x + threadIdx.x;
    if (e >= N_EDGES) return;
    atomicAdd(&s[dst[e]], y[src[e]]);
}

__global__ void k_reduce(const float* __restrict__ s, float* __restrict__ PM) {
    float p = 0.f, m = 0.f;
    for (int i = blockIdx.x * blockDim.x + threadIdx.x; i < N_NODES;
         i += gridDim.x * blockDim.x) {
        float v = s[i];
        p += fmaxf(v, 0.f);
        m += fminf(v, 0.f);
    }
#pragma unroll
    for (int off = 32; off > 0; off >>= 1) {
        p += __shfl_down(p, off);
        m += __shfl_down(m, off);
    }
    __shared__ float lp[4], lm[4];
    int wid = threadIdx.x >> 6, lane = threadIdx.x & 63;
    if (lane == 0) { lp[wid] = p; lm[wid] = m; }
    __syncthreads();
    if (threadIdx.x == 0) {
        float tp = 0.f, tm = 0.f;
        for (int w = 0; w < (int)(blockDim.x >> 6); ++w) { tp += lp[w]; tm += lm[w]; }
        atomicAdd(&PM[0], tp);
        atomicAdd(&PM[1], tm);
    }
}

__global__ void k_final_pm(const float* __restrict__ b1,
                           const float* __restrict__ a2,
                           const float* __restrict__ b2,
                           const float* __restrict__ PM,
                           float* __restrict__ out) {
    int t = threadIdx.x;
    float bv = b1[t];
    float prod = a2[t] * bv;
    float cp = (bv > 0.f) ? prod : 0.f;
    float cn = (bv < 0.f) ? prod : 0.f;
#pragma unroll
    for (int off = 32; off > 0; off >>= 1) {
        cp += __shfl_down(cp, off);
        cn += __shfl_down(cn, off);
    }
    __shared__ float scp[2], scn[2];
    __shared__ float tval;
    if ((t & 63) == 0) { scp[t >> 6] = cp; scn[t >> 6] = cn; }
    __syncthreads();
    if (t == 0) tval = PM[0] * (scp[0] + scp[1]) + PM[1] * (scn[0] + scn[1]);
    __syncthreads();
    if (t < N_CLASSES) out[t] = tval * b2[t];
}

extern "C" void kernel_launch(void* const* d_in, const int* in_sizes, int n_in,
                              void* d_out, int out_size, void* d_ws, size_t ws_size,
                              hipStream_t stream) {
    const float* x  = (const float*)d_in[0];
    const int*   ei = (const int*)d_in[1];   // [src(800000), dst(800000)]
    const float* a1 = (const float*)d_in[2];
    const float* b1 = (const float*)d_in[3];
    const float* a2 = (const float*)d_in[4];
    const float* b2 = (const float*)d_in[5];
    float* out = (float*)d_out;

    // ws layout: pairs[N_EDGES] (8B) | y[N_NODES] | prefg[NBLK1*PREFW] | PMpart[2*NB]
    unsigned long long* pairs = (unsigned long long*)d_ws;
    float* y      = (float*)(pairs + N_EDGES);
    int*   prefg  = (int*)(y + N_NODES);
    float* PMpart = (float*)(prefg + NBLK1 * PREFW);

    size_t need = (size_t)N_EDGES * 8 + (size_t)N_NODES * 4 +
                  (size_t)NBLK1 * PREFW * 4 + (size_t)2 * NB * 4;

    if (ws_size >= need) {
        k_node_dot<<<(N_NODES + 255) / 256, 256, 0, stream>>>(x, a1, y);
        k_bin<<<NBLK1, 256, 0, stream>>>(ei, ei + N_EDGES, y, pairs, prefg);
        k_accum<<<NB, 512, 0, stream>>>(pairs, prefg, PMpart);
        k_final<<<1, DIM_H, 0, stream>>>(b1, a2, b2, PMpart, out);
    } else {
        // fallback: single accumulator, device-scope atomics
        float* yf = (float*)d_ws;
        float* s  = yf + N_NODES;
        float* PM = s + N_NODES;
        hipMemsetAsync(s, 0, (N_NODES + 2) * sizeof(float), stream);
        k_node_dot<<<(N_NODES + 255) / 256, 256, 0, stream>>>(x, a1, yf);
        k_scatter<<<(N_EDGES + 255) / 256, 256, 0, stream>>>(ei, ei + N_EDGES, yf, s);
        k_reduce<<<196, 256, 0, stream>>>(s, PM);
        k_final_pm<<<1, DIM_H, 0, stream>>>(b1, a2, b2, PM, out);
    }
}

// Round 4
// 40.963 us; speedup vs baseline: 1.7390x; 1.1920x over previous
//
#include <hip/hip_runtime.h>

constexpr int N_NODES   = 50000;
constexpr int N_EDGES   = 800000;
constexpr int D_FEAT    = 96;
constexpr int DIM_H     = 128;
constexpr int N_CLASSES = 10;

constexpr int SHIFT  = 9;                                 // 512 nodes / bucket
constexpr int BNODES = 1 << SHIFT;
constexpr int NB     = (N_NODES + BNODES - 1) >> SHIFT;   // 98 buckets
constexpr int NBLK1  = 256;                               // phase-1 blocks
constexpr int EPB    = N_EDGES / NBLK1;                   // 3125 edges/block
constexpr int PREFW  = NB + 1;                            // 99

static_assert(N_NODES <= (1 << 16), "16-bit id packing requires N_NODES <= 65536");
static_assert(N_EDGES % NBLK1 == 0, "exact edge split");

__device__ inline int wave_iscan(int v, int lane) {
#pragma unroll
    for (int off = 1; off < 64; off <<= 1) {
        int n = __shfl_up(v, off);
        if (lane >= off) v += n;
    }
    return v;
}

__device__ inline float wave_rsum(float v) {
#pragma unroll
    for (int off = 32; off > 0; off >>= 1) v += __shfl_down(v, off);
    return v;
}

// ---------------------------------------------------------------------------
// K1: (a) y[i] = x[i,:].a1   (b) bin this block's 3125 edges by dst>>9 into
// packed (src<<16|dst) u32 pairs, grouped per bucket, + prefix table.
// Also zeroes the phase-2 ticket. No global atomics.
// ---------------------------------------------------------------------------
__global__ __launch_bounds__(256) void k_prep(
    const float* __restrict__ x, const float* __restrict__ a1,
    const int* __restrict__ src, const int* __restrict__ dst,
    float* __restrict__ y, unsigned* __restrict__ pairs,
    int* __restrict__ prefg, int* __restrict__ ticket)
{
    __shared__ int hist[NB], run[NB], excl[PREFW];
    __shared__ int wsum[4];
    const int tid  = threadIdx.x;
    const int lane = tid & 63, wid = tid >> 6;
    const int blk  = blockIdx.x;

    if (blk == 0 && tid == 0)
        __hip_atomic_store(ticket, 0, __ATOMIC_RELAXED, __HIP_MEMORY_SCOPE_AGENT);

    // ---- part A: node dot (independent of part B) ----
    {
        int i = blk * 256 + tid;   // 256*256 = 65536 >= N_NODES
        if (i < N_NODES) {
            const float4* row = reinterpret_cast<const float4*>(x + (size_t)i * D_FEAT);
            const float4* av  = reinterpret_cast<const float4*>(a1);
            float s = 0.f;
#pragma unroll
            for (int k = 0; k < D_FEAT / 4; ++k) {
                float4 v = row[k], a = av[k];
                s += v.x * a.x + v.y * a.y + v.z * a.z + v.w * a.w;
            }
            y[i] = s;
        }
    }

    // ---- part B: bucket histogram ----
    for (int t = tid; t < NB; t += 256) hist[t] = 0;
    __syncthreads();
    const int e0 = blk * EPB;
    for (int j = tid; j < EPB; j += 256)
        atomicAdd(&hist[dst[e0 + j] >> SHIFT], 1);
    __syncthreads();

    // exclusive scan over NB bucket counts
    int v   = (tid < NB) ? hist[tid] : 0;
    int inc = wave_iscan(v, lane);
    if (lane == 63) wsum[wid] = inc;
    __syncthreads();
    int woff = 0;
#pragma unroll
    for (int w = 0; w < 4; ++w) if (w < wid) woff += wsum[w];
    if (tid < NB) { int e = inc - v + woff; excl[tid] = e; run[tid] = e; }
    if (tid == 0) excl[NB] = wsum[0] + wsum[1] + wsum[2] + wsum[3];
    __syncthreads();
    if (tid < PREFW) prefg[blk * PREFW + tid] = excl[tid];

    // grouped scatter of packed pairs into this block's region
    for (int j = tid; j < EPB; j += 256) {
        int d = dst[e0 + j];
        int s = src[e0 + j];
        int pos = atomicAdd(&run[d >> SHIFT], 1);
        pairs[(size_t)blk * EPB + pos] = ((unsigned)s << 16) | (unsigned)d;
    }
}

// ---------------------------------------------------------------------------
// K2: one block per bucket (1024 thr = 16 waves for latency hiding).
// Wave-per-segment walk (no binary search): coalesced pair loads, y gather,
// LDS accumulate; relu-split partials; last block (device ticket) computes
// the final rank-1 output in-kernel.
// ---------------------------------------------------------------------------
__global__ __launch_bounds__(1024) void k_accum_final(
    const unsigned* __restrict__ pairs, const int* __restrict__ prefg,
    const float* __restrict__ y, const float* __restrict__ b1,
    const float* __restrict__ a2, const float* __restrict__ b2,
    float* __restrict__ PMpart, int* __restrict__ ticket,
    float* __restrict__ out)
{
    __shared__ float acc[BNODES];
    __shared__ int   soff[NBLK1], scnt[NBLK1];
    __shared__ float redp[16], redm[16], redcp[16], redcn[16];
    __shared__ int   islast;
    __shared__ float tval;
    const int b    = blockIdx.x;
    const int tid  = threadIdx.x;
    const int lane = tid & 63, wid = tid >> 6;

    if (tid < BNODES) acc[tid] = 0.f;
    if (tid < NBLK1) {
        int st = prefg[tid * PREFW + b];
        soff[tid] = st;
        scnt[tid] = prefg[tid * PREFW + b + 1] - st;
    }
    __syncthreads();

    // each wave owns segments wid, wid+16, ... : fully coalesced pair loads
    for (int seg = wid; seg < NBLK1; seg += 16) {
        int n = scnt[seg];
        const unsigned* p0 = pairs + (size_t)seg * EPB + soff[seg];
        for (int j = lane; j < n; j += 64) {
            unsigned p = p0[j];
            float v = y[p >> 16];
            atomicAdd(&acc[p & (BNODES - 1)], v);
        }
    }
    __syncthreads();

    // relu-split partials for this bucket
    float pp = 0.f, mm = 0.f;
    if (tid < BNODES) {
        int g = (b << SHIFT) + tid;
        if (g < N_NODES) {
            float v = acc[tid];
            pp = fmaxf(v, 0.f);
            mm = fminf(v, 0.f);
        }
    }
    pp = wave_rsum(pp);
    mm = wave_rsum(mm);
    if (lane == 0) { redp[wid] = pp; redm[wid] = mm; }
    __syncthreads();
    if (tid == 0) {
        float tp = 0.f, tm = 0.f;
#pragma unroll
        for (int w = 0; w < 16; ++w) { tp += redp[w]; tm += redm[w]; }
        __hip_atomic_store(&PMpart[2 * b],     tp, __ATOMIC_RELAXED, __HIP_MEMORY_SCOPE_AGENT);
        __hip_atomic_store(&PMpart[2 * b + 1], tm, __ATOMIC_RELAXED, __HIP_MEMORY_SCOPE_AGENT);
        int t = __hip_atomic_fetch_add(ticket, 1, __ATOMIC_ACQ_REL, __HIP_MEMORY_SCOPE_AGENT);
        islast = (t == NB - 1);
    }
    __syncthreads();

    if (islast) {
        float P = 0.f, M = 0.f, cp = 0.f, cn = 0.f;
        if (tid < NB) {
            P = __hip_atomic_load(&PMpart[2 * tid],     __ATOMIC_RELAXED, __HIP_MEMORY_SCOPE_AGENT);
            M = __hip_atomic_load(&PMpart[2 * tid + 1], __ATOMIC_RELAXED, __HIP_MEMORY_SCOPE_AGENT);
        }
        if (tid < DIM_H) {
            float bv = b1[tid], pr = a2[tid] * bv;
            cp = (bv > 0.f) ? pr : 0.f;
            cn = (bv < 0.f) ? pr : 0.f;
        }
        P  = wave_rsum(P);
        M  = wave_rsum(M);
        cp = wave_rsum(cp);
        cn = wave_rsum(cn);
        __syncthreads();                       // red arrays reuse
        if (lane == 0) { redp[wid] = P; redm[wid] = M; redcp[wid] = cp; redcn[wid] = cn; }
        __syncthreads();
        if (tid == 0) {
            float sP = 0.f, sM = 0.f, sCP = 0.f, sCN = 0.f;
#pragma unroll
            for (int w = 0; w < 16; ++w) {
                sP += redp[w]; sM += redm[w]; sCP += redcp[w]; sCN += redcn[w];
            }
            tval = sP * sCP + sM * sCN;
        }
        __syncthreads();
        if (tid < N_CLASSES) out[tid] = tval * b2[tid];
    }
}

// ---------------------------------------------------------------------------
// fallback path (ws too small): device-scope atomic scatter
// ---------------------------------------------------------------------------
__global__ void fb_node_dot(const float* __restrict__ x, const float* __restrict__ a1,
                            float* __restrict__ y) {
    int i = blockIdx.x * blockDim.x + threadIdx.x;
    if (i >= N_NODES) return;
    const float4* row = reinterpret_cast<const float4*>(x + (size_t)i * D_FEAT);
    const float4* av  = reinterpret_cast<const float4*>(a1);
    float acc = 0.f;
#pragma unroll
    for (int k = 0; k < D_FEAT / 4; ++k) {
        float4 v = row[k], a = av[k];
        acc += v.x * a.x + v.y * a.y + v.z * a.z + v.w * a.w;
    }
    y[i] = acc;
}

__global__ void fb_scatter(const int* __restrict__ src, const int* __restrict__ dst,
                           const float* __restrict__ y, float* __restrict__ s) {
    int e = blockIdx.x * blockDim.x + threadIdx.x;
    if (e >= N_EDGES) return;
    atomicAdd(&s[dst[e]], y[src[e]]);
}

__global__ void fb_reduce(const float* __restrict__ s, float* __restrict__ PM) {
    float p = 0.f, m = 0.f;
    for (int i = blockIdx.x * blockDim.x + threadIdx.x; i < N_NODES;
         i += gridDim.x * blockDim.x) {
        float v = s[i];
        p += fmaxf(v, 0.f);
        m += fminf(v, 0.f);
    }
    p = wave_rsum(p);
    m = wave_rsum(m);
    __shared__ float lp[4], lm[4];
    int wid = threadIdx.x >> 6, lane = threadIdx.x & 63;
    if (lane == 0) { lp[wid] = p; lm[wid] = m; }
    __syncthreads();
    if (threadIdx.x == 0) {
        float tp = 0.f, tm = 0.f;
        for (int w = 0; w < (int)(blockDim.x >> 6); ++w) { tp += lp[w]; tm += lm[w]; }
        atomicAdd(&PM[0], tp);
        atomicAdd(&PM[1], tm);
    }
}

__global__ void fb_final(const float* __restrict__ b1, const float* __restrict__ a2,
                         const float* __restrict__ b2, const float* __restrict__ PM,
                         float* __restrict__ out) {
    int t = threadIdx.x;
    float bv = b1[t], prod = a2[t] * bv;
    float cp = (bv > 0.f) ? prod : 0.f;
    float cn = (bv < 0.f) ? prod : 0.f;
    cp = wave_rsum(cp);
    cn = wave_rsum(cn);
    __shared__ float scp[2], scn[2], tv;
    if ((t & 63) == 0) { scp[t >> 6] = cp; scn[t >> 6] = cn; }
    __syncthreads();
    if (t == 0) tv = PM[0] * (scp[0] + scp[1]) + PM[1] * (scn[0] + scn[1]);
    __syncthreads();
    if (t < N_CLASSES) out[t] = tv * b2[t];
}

extern "C" void kernel_launch(void* const* d_in, const int* in_sizes, int n_in,
                              void* d_out, int out_size, void* d_ws, size_t ws_size,
                              hipStream_t stream) {
    const float* x  = (const float*)d_in[0];
    const int*   ei = (const int*)d_in[1];   // [src(800000), dst(800000)]
    const float* a1 = (const float*)d_in[2];
    const float* b1 = (const float*)d_in[3];
    const float* a2 = (const float*)d_in[4];
    const float* b2 = (const float*)d_in[5];
    float* out = (float*)d_out;

    // ws layout: pairs u32[N_EDGES] | y f32[N_NODES] | prefg i32[NBLK1*PREFW]
    //          | PMpart f32[2*NB] | ticket i32
    unsigned* pairs  = (unsigned*)d_ws;
    float*    y      = (float*)(pairs + N_EDGES);
    int*      prefg  = (int*)(y + N_NODES);
    float*    PMpart = (float*)(prefg + NBLK1 * PREFW);
    int*      ticket = (int*)(PMpart + 2 * NB);

    size_t need = (size_t)N_EDGES * 4 + (size_t)N_NODES * 4 +
                  (size_t)NBLK1 * PREFW * 4 + (size_t)2 * NB * 4 + 4;

    if (ws_size >= need) {
        k_prep<<<NBLK1, 256, 0, stream>>>(x, a1, ei, ei + N_EDGES, y, pairs, prefg, ticket);
        k_accum_final<<<NB, 1024, 0, stream>>>(pairs, prefg, y, b1, a2, b2,
                                               PMpart, ticket, out);
    } else {
        float* yf = (float*)d_ws;
        float* s  = yf + N_NODES;
        float* PM = s + N_NODES;
        hipMemsetAsync(s, 0, (N_NODES + 2) * sizeof(float), stream);
        fb_node_dot<<<(N_NODES + 255) / 256, 256, 0, stream>>>(x, a1, yf);
        fb_scatter<<<(N_EDGES + 255) / 256, 256, 0, stream>>>(ei, ei + N_EDGES, yf, s);
        fb_reduce<<<196, 256, 0, stream>>>(s, PM);
        fb_final<<<1, DIM_H, 0, stream>>>(b1, a2, b2, PM, out);
    }
}

// Round 5
// 27.237 us; speedup vs baseline: 2.6154x; 1.5039x over previous
//
#include <hip/hip_runtime.h>

constexpr int N_NODES   = 50000;
constexpr int N_EDGES   = 800000;
constexpr int D_FEAT    = 96;
constexpr int DIM_H     = 128;
constexpr int N_CLASSES = 10;

constexpr int SHIFT  = 8;                                 // 256 nodes / bucket
constexpr int BNODES = 1 << SHIFT;
constexpr int NB     = (N_NODES + BNODES - 1) >> SHIFT;   // 196 buckets
constexpr int NBLK1  = 256;                               // phase-1 blocks
constexpr int EPB    = N_EDGES / NBLK1;                   // 3125 edges/block
constexpr int PREFW  = NB + 1;                            // 197

static_assert(N_NODES <= (1 << 16), "16-bit id packing requires N_NODES <= 65536");
static_assert(N_EDGES % NBLK1 == 0, "exact edge split");
static_assert(D_FEAT % 8 == 0, "8-lane row dot needs D_FEAT % 8 == 0");

__device__ inline int wave_iscan(int v, int lane) {
#pragma unroll
    for (int off = 1; off < 64; off <<= 1) {
        int n = __shfl_up(v, off);
        if (lane >= off) v += n;
    }
    return v;
}

__device__ inline float wave_rsum(float v) {
#pragma unroll
    for (int off = 32; off > 0; off >>= 1) v += __shfl_down(v, off);
    return v;
}

// ---------------------------------------------------------------------------
// K1 (256 blocks x 1024 thr): (a) y = x.a1 with 8 lanes/row (coalesced),
// (b) bin this block's 3125 edges by dst>>8 INTO LDS, then write the pairs
// region out linearly (fully coalesced global stores). No global atomics.
// ---------------------------------------------------------------------------
__global__ __launch_bounds__(1024) void k_prep(
    const float* __restrict__ x, const float* __restrict__ a1,
    const int* __restrict__ src, const int* __restrict__ dst,
    float* __restrict__ y, unsigned* __restrict__ pairs,
    int* __restrict__ prefg, int* __restrict__ ticket)
{
    __shared__ unsigned stage[EPB];            // 12.5 KB
    __shared__ int hist[NB], run[NB], excl[PREFW];
    __shared__ int wsum[16];
    const int tid  = threadIdx.x;
    const int lane = tid & 63, wid = tid >> 6;
    const int blk  = blockIdx.x;

    if (blk == 0 && tid == 0)
        __hip_atomic_store(ticket, 0, __ATOMIC_RELAXED, __HIP_MEMORY_SCOPE_AGENT);

    // ---- part A: node dot, 8 lanes per row, 3 x float4 per lane ----
    {
        const float4* av = reinterpret_cast<const float4*>(a1);
        const int sub = tid & 7;
        const float4 a0 = av[sub * 3 + 0];
        const float4 a1v = av[sub * 3 + 1];
        const float4 a2v = av[sub * 3 + 2];
        const int g0 = (blk * 1024 + tid) >> 3;          // row-group id
        for (int r = g0; r < N_NODES; r += (NBLK1 * 1024) / 8) {
            const float4* row =
                reinterpret_cast<const float4*>(x + (size_t)r * D_FEAT) + sub * 3;
            float4 v0 = row[0], v1 = row[1], v2 = row[2];
            float s = v0.x * a0.x + v0.y * a0.y + v0.z * a0.z + v0.w * a0.w
                    + v1.x * a1v.x + v1.y * a1v.y + v1.z * a1v.z + v1.w * a1v.w
                    + v2.x * a2v.x + v2.y * a2v.y + v2.z * a2v.z + v2.w * a2v.w;
            s += __shfl_xor(s, 1);
            s += __shfl_xor(s, 2);
            s += __shfl_xor(s, 4);
            if (sub == 0) y[r] = s;
        }
    }

    // ---- part B: histogram of dst buckets ----
    for (int t = tid; t < NB; t += 1024) hist[t] = 0;
    __syncthreads();
    const int e0 = blk * EPB;
    for (int j = tid; j < EPB; j += 1024)
        atomicAdd(&hist[((unsigned)dst[e0 + j]) >> SHIFT], 1);
    __syncthreads();

    // exclusive scan over NB bucket counts (16-wave generic scan)
    int v   = (tid < NB) ? hist[tid] : 0;
    int inc = wave_iscan(v, lane);
    if (lane == 63) wsum[wid] = inc;
    __syncthreads();
    int woff = 0;
#pragma unroll
    for (int w = 0; w < 16; ++w) if (w < wid) woff += wsum[w];
    if (tid < NB) { int e = inc - v + woff; excl[tid] = e; run[tid] = e; }
    if (tid == 0) {
        int t = 0;
#pragma unroll
        for (int w = 0; w < 16; ++w) t += wsum[w];
        excl[NB] = t;
    }
    __syncthreads();
    if (tid < PREFW) prefg[blk * PREFW + tid] = excl[tid];

    // bin into LDS (cheap scatter), grouped by bucket
    for (int j = tid; j < EPB; j += 1024) {
        int d = dst[e0 + j];
        int s = src[e0 + j];
        int pos = atomicAdd(&run[((unsigned)d) >> SHIFT], 1);
        stage[pos] = ((unsigned)s << 16) | (unsigned)d;
    }
    __syncthreads();

    // coalesced linear write-out of the block's region
    for (int j = tid; j < EPB; j += 1024)
        pairs[(size_t)blk * EPB + j] = stage[j];
}

// ---------------------------------------------------------------------------
// K2 (196 blocks x 512 thr): bucket accumulation in LDS. Two threads walk
// each producer segment (all lanes live, no search). Relu-split partials;
// ticketed last block computes the final rank-1 output in-kernel.
// ---------------------------------------------------------------------------
__global__ __launch_bounds__(512) void k_accum_final(
    const unsigned* __restrict__ pairs, const int* __restrict__ prefg,
    const float* __restrict__ y, const float* __restrict__ b1,
    const float* __restrict__ a2, const float* __restrict__ b2,
    float* __restrict__ PMpart, int* __restrict__ ticket,
    float* __restrict__ out)
{
    __shared__ float acc[BNODES];
    __shared__ int   soff[NBLK1], scnt[NBLK1];
    __shared__ float redp[8], redm[8], redcp[8], redcn[8];
    __shared__ int   islast;
    __shared__ float tval;
    const int b    = blockIdx.x;
    const int tid  = threadIdx.x;
    const int lane = tid & 63, wid = tid >> 6;

    if (tid < BNODES) acc[tid] = 0.f;
    if (tid < NBLK1) {
        int st = prefg[tid * PREFW + b];
        soff[tid] = st;
        scnt[tid] = prefg[tid * PREFW + b + 1] - st;
    }
    __syncthreads();

    // 512 threads -> 2 per segment (seg = tid>>1, half = tid&1)
    {
        const int seg = tid >> 1, h = tid & 1;
        const int n = scnt[seg];
        const unsigned* p0 = pairs + (size_t)seg * EPB + soff[seg];
        for (int j = h; j < n; j += 2) {
            unsigned p = p0[j];
            atomicAdd(&acc[p & (BNODES - 1)], y[p >> 16]);
        }
    }
    __syncthreads();

    // relu-split partials for this bucket
    float pp = 0.f, mm = 0.f;
    if (tid < BNODES) {
        int g = (b << SHIFT) + tid;
        if (g < N_NODES) {
            float v = acc[tid];
            pp = fmaxf(v, 0.f);
            mm = fminf(v, 0.f);
        }
    }
    pp = wave_rsum(pp);
    mm = wave_rsum(mm);
    if (lane == 0) { redp[wid] = pp; redm[wid] = mm; }
    __syncthreads();
    if (tid == 0) {
        float tp = 0.f, tm = 0.f;
#pragma unroll
        for (int w = 0; w < 8; ++w) { tp += redp[w]; tm += redm[w]; }
        __hip_atomic_store(&PMpart[2 * b],     tp, __ATOMIC_RELAXED, __HIP_MEMORY_SCOPE_AGENT);
        __hip_atomic_store(&PMpart[2 * b + 1], tm, __ATOMIC_RELAXED, __HIP_MEMORY_SCOPE_AGENT);
        int t = __hip_atomic_fetch_add(ticket, 1, __ATOMIC_ACQ_REL, __HIP_MEMORY_SCOPE_AGENT);
        islast = (t == NB - 1);
    }
    __syncthreads();

    if (islast) {
        float P = 0.f, M = 0.f, cp = 0.f, cn = 0.f;
        if (tid < NB) {
            P = __hip_atomic_load(&PMpart[2 * tid],     __ATOMIC_RELAXED, __HIP_MEMORY_SCOPE_AGENT);
            M = __hip_atomic_load(&PMpart[2 * tid + 1], __ATOMIC_RELAXED, __HIP_MEMORY_SCOPE_AGENT);
        }
        if (tid < DIM_H) {
            float bv = b1[tid], pr = a2[tid] * bv;
            cp = (bv > 0.f) ? pr : 0.f;
            cn = (bv < 0.f) ? pr : 0.f;
        }
        P  = wave_rsum(P);
        M  = wave_rsum(M);
        cp = wave_rsum(cp);
        cn = wave_rsum(cn);
        __syncthreads();                        // red arrays reuse
        if (lane == 0) { redp[wid] = P; redm[wid] = M; redcp[wid] = cp; redcn[wid] = cn; }
        __syncthreads();
        if (tid == 0) {
            float sP = 0.f, sM = 0.f, sCP = 0.f, sCN = 0.f;
#pragma unroll
            for (int w = 0; w < 8; ++w) {
                sP += redp[w]; sM += redm[w]; sCP += redcp[w]; sCN += redcn[w];
            }
            tval = sP * sCP + sM * sCN;
        }
        __syncthreads();
        if (tid < N_CLASSES) out[tid] = tval * b2[tid];
    }
}

// ---------------------------------------------------------------------------
// fallback path (ws too small): device-scope atomic scatter
// ---------------------------------------------------------------------------
__global__ void fb_node_dot(const float* __restrict__ x, const float* __restrict__ a1,
                            float* __restrict__ y) {
    int i = blockIdx.x * blockDim.x + threadIdx.x;
    if (i >= N_NODES) return;
    const float4* row = reinterpret_cast<const float4*>(x + (size_t)i * D_FEAT);
    const float4* av  = reinterpret_cast<const float4*>(a1);
    float acc = 0.f;
#pragma unroll
    for (int k = 0; k < D_FEAT / 4; ++k) {
        float4 v = row[k], a = av[k];
        acc += v.x * a.x + v.y * a.y + v.z * a.z + v.w * a.w;
    }
    y[i] = acc;
}

__global__ void fb_scatter(const int* __restrict__ src, const int* __restrict__ dst,
                           const float* __restrict__ y, float* __restrict__ s) {
    int e = blockIdx.x * blockDim.x + threadIdx.x;
    if (e >= N_EDGES) return;
    atomicAdd(&s[dst[e]], y[src[e]]);
}

__global__ void fb_reduce(const float* __restrict__ s, float* __restrict__ PM) {
    float p = 0.f, m = 0.f;
    for (int i = blockIdx.x * blockDim.x + threadIdx.x; i < N_NODES;
         i += gridDim.x * blockDim.x) {
        float v = s[i];
        p += fmaxf(v, 0.f);
        m += fminf(v, 0.f);
    }
    p = wave_rsum(p);
    m = wave_rsum(m);
    __shared__ float lp[4], lm[4];
    int wid = threadIdx.x >> 6, lane = threadIdx.x & 63;
    if (lane == 0) { lp[wid] = p; lm[wid] = m; }
    __syncthreads();
    if (threadIdx.x == 0) {
        float tp = 0.f, tm = 0.f;
        for (int w = 0; w < (int)(blockDim.x >> 6); ++w) { tp += lp[w]; tm += lm[w]; }
        atomicAdd(&PM[0], tp);
        atomicAdd(&PM[1], tm);
    }
}

__global__ void fb_final(const float* __restrict__ b1, const float* __restrict__ a2,
                         const float* __restrict__ b2, const float* __restrict__ PM,
                         float* __restrict__ out) {
    int t = threadIdx.x;
    float bv = b1[t], prod = a2[t] * bv;
    float cp = (bv > 0.f) ? prod : 0.f;
    float cn = (bv < 0.f) ? prod : 0.f;
    cp = wave_rsum(cp);
    cn = wave_rsum(cn);
    __shared__ float scp[2], scn[2], tv;
    if ((t & 63) == 0) { scp[t >> 6] = cp; scn[t >> 6] = cn; }
    __syncthreads();
    if (t == 0) tv = PM[0] * (scp[0] + scp[1]) + PM[1] * (scn[0] + scn[1]);
    __syncthreads();
    if (t < N_CLASSES) out[t] = tv * b2[t];
}

extern "C" void kernel_launch(void* const* d_in, const int* in_sizes, int n_in,
                              void* d_out, int out_size, void* d_ws, size_t ws_size,
                              hipStream_t stream) {
    const float* x  = (const float*)d_in[0];
    const int*   ei = (const int*)d_in[1];   // [src(800000), dst(800000)]
    const float* a1 = (const float*)d_in[2];
    const float* b1 = (const float*)d_in[3];
    const float* a2 = (const float*)d_in[4];
    const float* b2 = (const float*)d_in[5];
    float* out = (float*)d_out;

    // ws layout: pairs u32[N_EDGES] | y f32[N_NODES] | prefg i32[NBLK1*PREFW]
    //          | PMpart f32[2*NB] | ticket i32
    unsigned* pairs  = (unsigned*)d_ws;
    float*    y      = (float*)(pairs + N_EDGES);
    int*      prefg  = (int*)(y + N_NODES);
    float*    PMpart = (float*)(prefg + NBLK1 * PREFW);
    int*      ticket = (int*)(PMpart + 2 * NB);

    size_t need = (size_t)N_EDGES * 4 + (size_t)N_NODES * 4 +
                  (size_t)NBLK1 * PREFW * 4 + (size_t)2 * NB * 4 + 4;

    if (ws_size >= need) {
        k_prep<<<NBLK1, 1024, 0, stream>>>(x, a1, ei, ei + N_EDGES, y, pairs, prefg, ticket);
        k_accum_final<<<NB, 512, 0, stream>>>(pairs, prefg, y, b1, a2, b2,
                                              PMpart, ticket, out);
    } else {
        float* yf = (float*)d_ws;
        float* s  = yf + N_NODES;
        float* PM = s + N_NODES;
        hipMemsetAsync(s, 0, (N_NODES + 2) * sizeof(float), stream);
        fb_node_dot<<<(N_NODES + 255) / 256, 256, 0, stream>>>(x, a1, yf);
        fb_scatter<<<(N_EDGES + 255) / 256, 256, 0, stream>>>(ei, ei + N_EDGES, yf, s);
        fb_reduce<<<196, 256, 0, stream>>>(s, PM);
        fb_final<<<1, DIM_H, 0, stream>>>(b1, a2, b2, PM, out);
    }
}